// Round 1
// baseline (828.273 us; speedup 1.0000x reference)
//
#include <hip/hip_runtime.h>

// Problem constants
// B=64, S=1024, D=800, MS=16, T=32, H=200, NS=12
// Nseq = B*MS = 1024, M = Nseq*T = 32768
// Gates N = 4H*2 = 1600, padded to 1664. Whh K = 200, padded to 224.

typedef __attribute__((ext_vector_type(4))) float f32x4;
typedef __attribute__((ext_vector_type(8))) short s16x8;

__device__ __forceinline__ unsigned short f2bf(float f) {
    union { float f; unsigned int u; } a; a.f = f;
    unsigned int u = a.u;
    u += 0x7fffu + ((u >> 16) & 1u);   // RNE
    return (unsigned short)(u >> 16);
}
__device__ __forceinline__ float bf2f(unsigned short s) {
    union { unsigned int u; float f; } a; a.u = ((unsigned int)s) << 16; return a.f;
}
__device__ __forceinline__ void async_copy16(const void* g, void* l) {
    __builtin_amdgcn_global_load_lds(
        (const __attribute__((address_space(1))) unsigned int*)g,
        (__attribute__((address_space(3))) unsigned int*)l, 16, 0, 0);
}
__device__ __forceinline__ float sigf_(float x) {
    return 1.f / (1.f + __expf(-x));
}
__device__ __forceinline__ float tanhf_(float x) {
    float ax = fabsf(x);
    float e = __expf(-2.f * ax);
    float r = (1.f - e) / (1.f + e);
    return x < 0.f ? -r : r;
}

// ---------------- kernel 1: pack weights to bf16 (padded) + bias ----------------
// Wp   [1664][800] bf16 : rows 0..799 = Wih_f, 800..1599 = Wih_b, 1600..1663 = 0
// WhhP [1600][224] bf16 : rows 0..799 = Whh_f, 800..1599 = Whh_b, k 200..223 = 0
// biasP[1664] f32       : bih+bhh per dir, pad 0
__global__ void pack_kernel(const float* __restrict__ Wih_f, const float* __restrict__ Wih_b,
                            const float* __restrict__ Whh_f, const float* __restrict__ Whh_b,
                            const float* __restrict__ bih_f, const float* __restrict__ bhh_f,
                            const float* __restrict__ bih_b, const float* __restrict__ bhh_b,
                            unsigned short* __restrict__ Wp, unsigned short* __restrict__ WhhP,
                            float* __restrict__ biasP)
{
    int tid = blockIdx.x * blockDim.x + threadIdx.x;
    if (tid < 1664 * 800) {
        int n = tid / 800, k = tid - n * 800;
        float v = 0.f;
        if (n < 800)       v = Wih_f[n * 800 + k];
        else if (n < 1600) v = Wih_b[(n - 800) * 800 + k];
        Wp[tid] = f2bf(v);
        return;
    }
    int t2 = tid - 1664 * 800;
    if (t2 < 1600 * 224) {
        int n = t2 / 224, k = t2 - n * 224;
        float v = 0.f;
        if (k < 200) v = (n < 800) ? Whh_f[n * 200 + k] : Whh_b[(n - 800) * 200 + k];
        WhhP[t2] = f2bf(v);
        return;
    }
    int t3 = t2 - 1600 * 224;
    if (t3 < 1664) {
        float v = 0.f;
        if (t3 < 800)       v = bih_f[t3] + bhh_f[t3];
        else if (t3 < 1600) v = bih_b[t3 - 800] + bhh_b[t3 - 800];
        biasP[t3] = v;
    }
}

// ---------------- kernel 2: gather spans + fp32->bf16 ----------------
// Xg [32768][800] bf16, row = seq*32 + t, seq = b*16 + m
__global__ void gather_kernel(const float* __restrict__ hidden, const int* __restrict__ starts,
                              unsigned short* __restrict__ Xg)
{
    int tid = blockIdx.x * blockDim.x + threadIdx.x;   // one per 4 elements
    if (tid >= 32768 * 200) return;
    int row = tid / 200;
    int c4  = tid - row * 200;
    int seq = row >> 5, t = row & 31;
    int b   = seq >> 4;
    int src = starts[seq] + t;
    src = src < 1023 ? src : 1023;
    const float4 v = *(const float4*)(hidden + (size_t)(b * 1024 + src) * 800 + c4 * 4);
    ushort4 o;
    o.x = f2bf(v.x); o.y = f2bf(v.y); o.z = f2bf(v.z); o.w = f2bf(v.w);
    *(ushort4*)(Xg + (size_t)row * 800 + c4 * 4) = o;
}

// ---------------- kernel 3: GEMM Z = Xg @ Wp^T + bias (bf16 in, bf16 out) ----------------
// M=32768, N=1664(padded), K=800. 128x128 tile, BK=32, 4 waves, 4x4 16x16x32 per wave.
__global__ __launch_bounds__(256) void gemm_kernel(const unsigned short* __restrict__ Xg,
                                                   const unsigned short* __restrict__ Wp,
                                                   const float* __restrict__ biasP,
                                                   unsigned short* __restrict__ Z)
{
    __shared__ __align__(16) unsigned short As[128 * 32];
    __shared__ __align__(16) unsigned short Bs[128 * 32];
    const int tid = threadIdx.x;
    const int wid = tid >> 6, lane = tid & 63;
    const int m0 = blockIdx.x * 128;
    const int n0 = blockIdx.y * 128;
    const int wm = (wid >> 1) * 64, wn = (wid & 1) * 64;
    const int l15 = lane & 15, l4 = lane >> 4;

    f32x4 acc[4][4];
#pragma unroll
    for (int i = 0; i < 4; i++)
#pragma unroll
        for (int j = 0; j < 4; j++) acc[i][j] = (f32x4){0.f, 0.f, 0.f, 0.f};

    // staging chunk ids: c0 = tid, c1 = 256+tid; row = c>>2, kcol = (c&3)*8
    const int r0 = tid >> 2,        kc0 = (tid & 3) * 8;
    const int r1 = (256 + tid) >> 2, kc1 = (tid & 3) * 8;
    unsigned short* AsB0 = As + (size_t)(wid * 64) * 8;
    unsigned short* AsB1 = As + (size_t)(256 + wid * 64) * 8;
    unsigned short* BsB0 = Bs + (size_t)(wid * 64) * 8;
    unsigned short* BsB1 = Bs + (size_t)(256 + wid * 64) * 8;

    for (int kb = 0; kb < 25; ++kb) {
        const int kk = kb * 32;
        async_copy16(Xg + (size_t)(m0 + r0) * 800 + kk + kc0, AsB0);
        async_copy16(Xg + (size_t)(m0 + r1) * 800 + kk + kc1, AsB1);
        async_copy16(Wp + (size_t)(n0 + r0) * 800 + kk + kc0, BsB0);
        async_copy16(Wp + (size_t)(n0 + r1) * 800 + kk + kc1, BsB1);
        __syncthreads();

        s16x8 a[4], b[4];
#pragma unroll
        for (int i = 0; i < 4; i++)
            a[i] = *(const s16x8*)(As + (wm + i * 16 + l15) * 32 + l4 * 8);
#pragma unroll
        for (int i = 0; i < 4; i++)
            b[i] = *(const s16x8*)(Bs + (wn + i * 16 + l15) * 32 + l4 * 8);
#pragma unroll
        for (int im = 0; im < 4; im++)
#pragma unroll
            for (int in = 0; in < 4; in++)
                acc[im][in] = __builtin_amdgcn_mfma_f32_16x16x32_bf16(a[im], b[in], acc[im][in], 0, 0, 0);
        __syncthreads();
    }

    float bias_v[4];
#pragma unroll
    for (int in = 0; in < 4; in++) bias_v[in] = biasP[n0 + wn + in * 16 + l15];

#pragma unroll
    for (int im = 0; im < 4; im++) {
        int mbase = m0 + wm + im * 16 + l4 * 4;
#pragma unroll
        for (int in = 0; in < 4; in++) {
            int col = n0 + wn + in * 16 + l15;
#pragma unroll
            for (int r = 0; r < 4; r++)
                Z[(size_t)(mbase + r) * 1664 + col] = f2bf(acc[im][in][r] + bias_v[in]);
        }
    }
}

// ---------------- kernel 4: masked bidirectional LSTM + pooled feats ----------------
// grid.x = 128: dir = bx>>6 (0=f,1=b), g = bx&63 (16 sequences = one batch row)
// Z rows = seq*32+t, cols dir*800 + gate. feats [1024][400] f32.
__global__ __launch_bounds__(256) void lstm_kernel(const unsigned short* __restrict__ Z,
                                                   const unsigned short* __restrict__ WhhP,
                                                   const int* __restrict__ span_lens,
                                                   float* __restrict__ feats)
{
    __shared__ __align__(16) unsigned short h_lds[16 * 232];   // A operand [m=16][k pad 224], stride 232
    __shared__ float z_lds[16 * 802];                          // [16][800] stride 802
    const int bx = blockIdx.x;
    const int dir = bx >> 6;
    const int g = bx & 63;
    const int tid = threadIdx.x;
    const int wid = tid >> 6, lane = tid & 63;
    const int l15 = lane & 15, l4 = lane >> 4;

    for (int i = tid; i < 16 * 232; i += 256) h_lds[i] = 0;

    // per-thread (sample, unit) pairs: p = tid + 256*k, p < 3200
    float c_reg[13], f_reg[13];
    int zoff[13], hoff[13], lenk[13];
#pragma unroll
    for (int k = 0; k < 13; k++) {
        c_reg[k] = 0.f; f_reg[k] = 0.f;
        int p = tid + k * 256;
        if (p < 3200) {
            int s = p / 200, u = p - s * 200;
            zoff[k] = s * 802 + u;
            hoff[k] = s * 232 + u;
            lenk[k] = span_lens[g * 16 + s];
        } else { zoff[k] = 0; hoff[k] = 0; lenk[k] = -1; }
    }
    __syncthreads();

    for (int step = 0; step < 32; ++step) {
        const int t = dir ? (31 - step) : step;
        // phase 1: z = Z[:, t, :] + h @ Whh^T  (MFMA over 50 n-tiles of 16)
        for (int j = wid; j < 50; j += 4) {
            const int colg = dir * 800 + j * 16 + l15;
            f32x4 acc;
#pragma unroll
            for (int r = 0; r < 4; r++) {
                int samp = l4 * 4 + r;
                acc[r] = bf2f(Z[(size_t)((g * 16 + samp) * 32 + t) * 1664 + colg]);
            }
            const unsigned short* wrow = WhhP + (size_t)colg * 224 + l4 * 8;
            const unsigned short* hrow = h_lds + l15 * 232 + l4 * 8;
#pragma unroll
            for (int kk = 0; kk < 7; ++kk) {
                s16x8 a = *(const s16x8*)(hrow + kk * 32);
                s16x8 b = *(const s16x8*)(wrow + kk * 32);
                acc = __builtin_amdgcn_mfma_f32_16x16x32_bf16(a, b, acc, 0, 0, 0);
            }
#pragma unroll
            for (int r = 0; r < 4; r++)
                z_lds[(l4 * 4 + r) * 802 + j * 16 + l15] = acc[r];
        }
        __syncthreads();
        // phase 2: gates + state update (masked)
#pragma unroll
        for (int k = 0; k < 13; k++) {
            if (t < lenk[k]) {
                float zi = z_lds[zoff[k]];
                float zf = z_lds[zoff[k] + 200];
                float zg = z_lds[zoff[k] + 400];
                float zo = z_lds[zoff[k] + 600];
                float cn = sigf_(zf) * c_reg[k] + sigf_(zi) * tanhf_(zg);
                float hn = sigf_(zo) * tanhf_(cn);
                c_reg[k] = cn;
                f_reg[k] += hn;
                h_lds[hoff[k]] = f2bf(hn);
            }
        }
        __syncthreads();
    }

#pragma unroll
    for (int k = 0; k < 13; k++) {
        int p = tid + k * 256;
        if (p < 3200) {
            int s = p / 200, u = p - s * 200;
            feats[(size_t)(g * 16 + s) * 400 + dir * 200 + u] = f_reg[k];
        }
    }
}

// ---------------- kernel 5: logits = feats @ slot_embs * slot_mask ----------------
__global__ void logits_kernel(const float* __restrict__ feats, const float* __restrict__ se,
                              const float* __restrict__ slot_mask, float* __restrict__ out)
{
    int tid = blockIdx.x * blockDim.x + threadIdx.x;
    if (tid >= 1024 * 12) return;
    int n = tid / 12, ns = tid - n * 12;
    const float* f = feats + (size_t)n * 400;
    float acc = 0.f;
    for (int u = 0; u < 400; ++u) acc += f[u] * se[u * 12 + ns];
    out[tid] = acc * slot_mask[n];
}

extern "C" void kernel_launch(void* const* d_in, const int* in_sizes, int n_in,
                              void* d_out, int out_size, void* d_ws, size_t ws_size,
                              hipStream_t stream)
{
    const float* hidden      = (const float*)d_in[0];
    const float* Wih_f       = (const float*)d_in[1];
    const float* Whh_f       = (const float*)d_in[2];
    const float* bih_f       = (const float*)d_in[3];
    const float* bhh_f       = (const float*)d_in[4];
    const float* Wih_b       = (const float*)d_in[5];
    const float* Whh_b       = (const float*)d_in[6];
    const float* bih_b       = (const float*)d_in[7];
    const float* bhh_b       = (const float*)d_in[8];
    const float* slot_embs   = (const float*)d_in[9];
    const int*   span_starts = (const int*)d_in[10];
    const int*   span_lens   = (const int*)d_in[11];
    const float* slot_mask   = (const float*)d_in[12];
    float* out = (float*)d_out;

    char* ws = (char*)d_ws;
    unsigned short* Xg    = (unsigned short*)(ws + 0);           //  52,428,800 B
    unsigned short* Wp    = (unsigned short*)(ws + 52428800);    //   2,662,400 B
    unsigned short* WhhP  = (unsigned short*)(ws + 55091200);    //     716,800 B
    float*          biasP = (float*)         (ws + 55808000);    //       6,656 B
    unsigned short* Z     = (unsigned short*)(ws + 55814656);    // 109,051,904 B
    float*          feats = (float*)         (ws + 164866560);   //   1,638,400 B
    // total ws use: 166,504,960 B

    // 1. pack
    {
        int total = 1664 * 800 + 1600 * 224 + 1664;
        int blocks = (total + 255) / 256;
        pack_kernel<<<blocks, 256, 0, stream>>>(Wih_f, Wih_b, Whh_f, Whh_b,
                                                bih_f, bhh_f, bih_b, bhh_b,
                                                Wp, WhhP, biasP);
    }
    // 2. gather
    gather_kernel<<<25600, 256, 0, stream>>>(hidden, span_starts, Xg);
    // 3. GEMM
    gemm_kernel<<<dim3(256, 13), 256, 0, stream>>>(Xg, Wp, biasP, Z);
    // 4. LSTM
    lstm_kernel<<<128, 256, 0, stream>>>(Z, WhhP, span_lens, feats);
    // 5. logits
    logits_kernel<<<48, 256, 0, stream>>>(feats, slot_embs, slot_mask, out);
}

// Round 2
// 703.081 us; speedup vs baseline: 1.1781x; 1.1781x over previous
//
#include <hip/hip_runtime.h>

// B=64, S=1024, D=800, MS=16, T=32, H=200, NS=12
// Nseq=1024, M=32768 (m = t*1024 + seq), gates N=1600 pad 1664, Whh K pad 224.

typedef __attribute__((ext_vector_type(4))) float f32x4;
typedef __attribute__((ext_vector_type(8))) short s16x8;

__device__ __forceinline__ unsigned short f2bf(float f) {
    union { float f; unsigned int u; } a; a.f = f;
    unsigned int u = a.u;
    u += 0x7fffu + ((u >> 16) & 1u);   // RNE
    return (unsigned short)(u >> 16);
}
__device__ __forceinline__ float bf2f(unsigned short s) {
    union { unsigned int u; float f; } a; a.u = ((unsigned int)s) << 16; return a.f;
}
__device__ __forceinline__ void async_copy16(const void* g, void* l) {
    __builtin_amdgcn_global_load_lds(
        (const __attribute__((address_space(1))) unsigned int*)g,
        (__attribute__((address_space(3))) unsigned int*)l, 16, 0, 0);
}
__device__ __forceinline__ float sigf_(float x) {
    return 1.f / (1.f + __expf(-x));
}
__device__ __forceinline__ float tanhf_(float x) {
    float ax = fabsf(x);
    float e = __expf(-2.f * ax);
    float r = (1.f - e) / (1.f + e);
    return x < 0.f ? -r : r;
}

// ---------------- kernel 1: pack weights to bf16 (padded) + bias ----------------
__global__ void pack_kernel(const float* __restrict__ Wih_f, const float* __restrict__ Wih_b,
                            const float* __restrict__ Whh_f, const float* __restrict__ Whh_b,
                            const float* __restrict__ bih_f, const float* __restrict__ bhh_f,
                            const float* __restrict__ bih_b, const float* __restrict__ bhh_b,
                            unsigned short* __restrict__ Wp, unsigned short* __restrict__ WhhP,
                            float* __restrict__ biasP)
{
    int tid = blockIdx.x * blockDim.x + threadIdx.x;
    if (tid < 1664 * 800) {
        int n = tid / 800, k = tid - n * 800;
        float v = 0.f;
        if (n < 800)       v = Wih_f[n * 800 + k];
        else if (n < 1600) v = Wih_b[(n - 800) * 800 + k];
        Wp[tid] = f2bf(v);
        return;
    }
    int t2 = tid - 1664 * 800;
    if (t2 < 1600 * 224) {
        int n = t2 / 224, k = t2 - n * 224;
        float v = 0.f;
        if (k < 200) v = (n < 800) ? Whh_f[n * 200 + k] : Whh_b[(n - 800) * 200 + k];
        WhhP[t2] = f2bf(v);
        return;
    }
    int t3 = t2 - 1600 * 224;
    if (t3 < 1664) {
        float v = 0.f;
        if (t3 < 800)       v = bih_f[t3] + bhh_f[t3];
        else if (t3 < 1600) v = bih_b[t3 - 800] + bhh_b[t3 - 800];
        biasP[t3] = v;
    }
}

// ---------------- kernel 2: gather spans + fp32->bf16 ----------------
// Xg row m = t*1024 + seq, seq = b*16 + ms
__global__ void gather_kernel(const float* __restrict__ hidden, const int* __restrict__ starts,
                              unsigned short* __restrict__ Xg)
{
    int tid = blockIdx.x * blockDim.x + threadIdx.x;   // one per 4 elements
    if (tid >= 32768 * 200) return;
    int row = tid / 200;
    int c4  = tid - row * 200;
    int t   = row >> 10, seq = row & 1023;
    int b   = seq >> 4;
    int src = starts[seq] + t;
    src = src < 1023 ? src : 1023;
    const float4 v = *(const float4*)(hidden + (size_t)(b * 1024 + src) * 800 + c4 * 4);
    ushort4 o;
    o.x = f2bf(v.x); o.y = f2bf(v.y); o.z = f2bf(v.z); o.w = f2bf(v.w);
    *(ushort4*)(Xg + (size_t)row * 800 + c4 * 4) = o;
}

// ---------------- kernel 3: GEMM Z = Xg @ Wp^T + bias ----------------
// M=32768, N=1664, K=800. Epilogue scatters to Zf/Zb[m][u] (stride 832, bf16).
__global__ __launch_bounds__(256) void gemm_kernel(const unsigned short* __restrict__ Xg,
                                                   const unsigned short* __restrict__ Wp,
                                                   const float* __restrict__ biasP,
                                                   unsigned short* __restrict__ Zf,
                                                   unsigned short* __restrict__ Zb)
{
    __shared__ __align__(16) unsigned short As[128 * 32];
    __shared__ __align__(16) unsigned short Bs[128 * 32];
    const int tid = threadIdx.x;
    const int wid = tid >> 6, lane = tid & 63;
    const int m0 = blockIdx.x * 128;
    const int n0 = blockIdx.y * 128;
    const int wm = (wid >> 1) * 64, wn = (wid & 1) * 64;
    const int l15 = lane & 15, l4 = lane >> 4;

    f32x4 acc[4][4];
#pragma unroll
    for (int i = 0; i < 4; i++)
#pragma unroll
        for (int j = 0; j < 4; j++) acc[i][j] = (f32x4){0.f, 0.f, 0.f, 0.f};

    const int r0 = tid >> 2,         kc0 = (tid & 3) * 8;
    const int r1 = (256 + tid) >> 2, kc1 = (tid & 3) * 8;
    unsigned short* AsB0 = As + (size_t)(wid * 64) * 8;
    unsigned short* AsB1 = As + (size_t)(256 + wid * 64) * 8;
    unsigned short* BsB0 = Bs + (size_t)(wid * 64) * 8;
    unsigned short* BsB1 = Bs + (size_t)(256 + wid * 64) * 8;

    for (int kb = 0; kb < 25; ++kb) {
        const int kk = kb * 32;
        async_copy16(Xg + (size_t)(m0 + r0) * 800 + kk + kc0, AsB0);
        async_copy16(Xg + (size_t)(m0 + r1) * 800 + kk + kc1, AsB1);
        async_copy16(Wp + (size_t)(n0 + r0) * 800 + kk + kc0, BsB0);
        async_copy16(Wp + (size_t)(n0 + r1) * 800 + kk + kc1, BsB1);
        __syncthreads();

        s16x8 a[4], b[4];
#pragma unroll
        for (int i = 0; i < 4; i++)
            a[i] = *(const s16x8*)(As + (wm + i * 16 + l15) * 32 + l4 * 8);
#pragma unroll
        for (int i = 0; i < 4; i++)
            b[i] = *(const s16x8*)(Bs + (wn + i * 16 + l15) * 32 + l4 * 8);
#pragma unroll
        for (int im = 0; im < 4; im++)
#pragma unroll
            for (int in = 0; in < 4; in++)
                acc[im][in] = __builtin_amdgcn_mfma_f32_16x16x32_bf16(a[im], b[in], acc[im][in], 0, 0, 0);
        __syncthreads();
    }

    float bias_v[4];
#pragma unroll
    for (int in = 0; in < 4; in++) bias_v[in] = biasP[n0 + wn + in * 16 + l15];

#pragma unroll
    for (int im = 0; im < 4; im++) {
        int mbase = m0 + wm + im * 16 + l4 * 4;
#pragma unroll
        for (int in = 0; in < 4; in++) {
            int col = n0 + wn + in * 16 + l15;
            if (col < 1600) {
                int d = col >= 800;
                int u = col - d * 800;
                unsigned short* Zd = d ? Zb : Zf;
#pragma unroll
                for (int r = 0; r < 4; r++)
                    Zd[(size_t)(mbase + r) * 832 + u] = f2bf(acc[im][in][r] + bias_v[in]);
            }
        }
    }
}

// ---------------- kernel 4: masked bidirectional LSTM + pooled feats ----------------
// 128 blocks x 512 threads: dir = bx>>6, g = bx&63 (16 sequences).
// Per step: DMA next Z tile (contiguous 16x832 bf16) into LDS double buffer,
// MFMA h@Whh^T (acc from 0), gate phase adds staged input-z.
__global__ __launch_bounds__(512) void lstm_kernel(const unsigned short* __restrict__ Zf,
                                                   const unsigned short* __restrict__ Zb,
                                                   const unsigned short* __restrict__ WhhP,
                                                   const int* __restrict__ span_lens,
                                                   float* __restrict__ feats)
{
    __shared__ __align__(16) unsigned short h_lds[16 * 232];     // A operand, k pad 224, stride 232
    __shared__ __align__(16) unsigned short zbuf[2][16 * 832];   // staged input-z tiles
    __shared__ float zm[16 * 812];                               // MFMA out, stride 812 (bank-spread)

    const int bx = blockIdx.x;
    const int dir = bx >> 6;
    const int g = bx & 63;
    const int tid = threadIdx.x;
    const int w = tid >> 6, lane = tid & 63;
    const int l15 = lane & 15, l4 = lane >> 4;
    const unsigned short* __restrict__ Zd = dir ? Zb : Zf;

    for (int i = tid; i < 16 * 232; i += 512) h_lds[i] = 0;

    // per-thread gate-state mapping: p = tid + 512*k < 3200 -> (s,u)
    float c_reg[7], f_reg[7];
    int zmo[7], zbo[7], ho[7], lenk[7], srow[7], ucol[7];
#pragma unroll
    for (int k = 0; k < 7; k++) {
        c_reg[k] = 0.f; f_reg[k] = 0.f;
        int p = tid + k * 512;
        if (p < 3200) {
            int s = p / 200, u = p - s * 200;
            srow[k] = s; ucol[k] = u;
            zmo[k] = s * 812 + u;
            zbo[k] = s * 832 + u;
            ho[k]  = s * 232 + u;
            lenk[k] = span_lens[g * 16 + s];
        } else { zmo[k] = 0; zbo[k] = 0; ho[k] = 0; lenk[k] = -1; srow[k] = 0; ucol[k] = 0; }
    }

    // prefetch step-0 tile into zbuf[0]
    {
        const int t0 = dir ? 31 : 0;
        const unsigned short* gb = Zd + (size_t)(t0 * 1024 + g * 16) * 832;
        for (int c = w; c < 26; c += 8)
            async_copy16(gb + c * 512 + lane * 8, (unsigned short*)zbuf[0] + c * 512);
    }
    __syncthreads();

    for (int step = 0; step < 32; ++step) {
        const int t = dir ? (31 - step) : step;
        const int cur = step & 1, nxt = cur ^ 1;
        if (step < 31) {
            const int tn = dir ? (t - 1) : (t + 1);
            const unsigned short* gb = Zd + (size_t)(tn * 1024 + g * 16) * 832;
            for (int c = w; c < 26; c += 8)
                async_copy16(gb + c * 512 + lane * 8, (unsigned short*)zbuf[nxt] + c * 512);
        }
        // phase 1: zm = h @ Whh^T (50 n-tiles over 8 waves); two independent MFMA chains
        for (int j = w; j < 50; j += 8) {
            const int colg = dir * 800 + j * 16 + l15;
            const unsigned short* wrow = WhhP + (size_t)colg * 224 + l4 * 8;
            const unsigned short* hrow = h_lds + l15 * 232 + l4 * 8;
            f32x4 acc0 = (f32x4){0.f, 0.f, 0.f, 0.f};
            f32x4 acc1 = (f32x4){0.f, 0.f, 0.f, 0.f};
#pragma unroll
            for (int kk = 0; kk < 7; ++kk) {
                s16x8 a = *(const s16x8*)(hrow + kk * 32);
                s16x8 b = *(const s16x8*)(wrow + kk * 32);
                if (kk & 1) acc1 = __builtin_amdgcn_mfma_f32_16x16x32_bf16(a, b, acc1, 0, 0, 0);
                else        acc0 = __builtin_amdgcn_mfma_f32_16x16x32_bf16(a, b, acc0, 0, 0, 0);
            }
            f32x4 accs = acc0 + acc1;
#pragma unroll
            for (int r = 0; r < 4; ++r)
                zm[(l4 * 4 + r) * 812 + j * 16 + l15] = accs[r];
        }
        __syncthreads();   // zm visible; all DMA drained (incl. zbuf[cur] from prev step)
        // phase 2: gates + state update (masked)
#pragma unroll
        for (int k = 0; k < 7; ++k) {
            if (t < lenk[k]) {
                float zi = zm[zmo[k]]       + bf2f(zbuf[cur][zbo[k]]);
                float zf = zm[zmo[k] + 200] + bf2f(zbuf[cur][zbo[k] + 200]);
                float zg = zm[zmo[k] + 400] + bf2f(zbuf[cur][zbo[k] + 400]);
                float zo = zm[zmo[k] + 600] + bf2f(zbuf[cur][zbo[k] + 600]);
                float cn = sigf_(zf) * c_reg[k] + sigf_(zi) * tanhf_(zg);
                float hn = sigf_(zo) * tanhf_(cn);
                c_reg[k] = cn;
                f_reg[k] += hn;
                h_lds[ho[k]] = f2bf(hn);
            }
        }
        __syncthreads();   // h_lds stable for next phase 1; zbuf[cur] free to overwrite
    }

#pragma unroll
    for (int k = 0; k < 7; ++k)
        if (lenk[k] >= 0)
            feats[(size_t)(g * 16 + srow[k]) * 400 + dir * 200 + ucol[k]] = f_reg[k];
}

// ---------------- kernel 5: logits = feats @ slot_embs * slot_mask ----------------
__global__ void logits_kernel(const float* __restrict__ feats, const float* __restrict__ se,
                              const float* __restrict__ slot_mask, float* __restrict__ out)
{
    int tid = blockIdx.x * blockDim.x + threadIdx.x;
    if (tid >= 1024 * 12) return;
    int n = tid / 12, ns = tid - n * 12;
    const float* f = feats + (size_t)n * 400;
    float acc = 0.f;
    for (int u = 0; u < 400; ++u) acc += f[u] * se[u * 12 + ns];
    out[tid] = acc * slot_mask[n];
}

extern "C" void kernel_launch(void* const* d_in, const int* in_sizes, int n_in,
                              void* d_out, int out_size, void* d_ws, size_t ws_size,
                              hipStream_t stream)
{
    const float* hidden      = (const float*)d_in[0];
    const float* Wih_f       = (const float*)d_in[1];
    const float* Whh_f       = (const float*)d_in[2];
    const float* bih_f       = (const float*)d_in[3];
    const float* bhh_f       = (const float*)d_in[4];
    const float* Wih_b       = (const float*)d_in[5];
    const float* Whh_b       = (const float*)d_in[6];
    const float* bih_b       = (const float*)d_in[7];
    const float* bhh_b       = (const float*)d_in[8];
    const float* slot_embs   = (const float*)d_in[9];
    const int*   span_starts = (const int*)d_in[10];
    const int*   span_lens   = (const int*)d_in[11];
    const float* slot_mask   = (const float*)d_in[12];
    float* out = (float*)d_out;

    char* ws = (char*)d_ws;
    unsigned short* Xg    = (unsigned short*)(ws + 0);           //  52,428,800
    unsigned short* Wp    = (unsigned short*)(ws + 52428800);    //   2,662,400
    unsigned short* WhhP  = (unsigned short*)(ws + 55091200);    //     716,800
    float*          biasP = (float*)         (ws + 55808000);    //       6,656
    unsigned short* Zf    = (unsigned short*)(ws + 55814656);    //  54,525,952 (32768 x 832 bf16)
    unsigned short* Zb    = (unsigned short*)(ws + 110340608);   //  54,525,952
    float*          feats = (float*)         (ws + 164866560);   //   1,638,400
    // total: 166,504,960 B

    {
        int total = 1664 * 800 + 1600 * 224 + 1664;
        int blocks = (total + 255) / 256;
        pack_kernel<<<blocks, 256, 0, stream>>>(Wih_f, Wih_b, Whh_f, Whh_b,
                                                bih_f, bhh_f, bih_b, bhh_b,
                                                Wp, WhhP, biasP);
    }
    gather_kernel<<<25600, 256, 0, stream>>>(hidden, span_starts, Xg);
    gemm_kernel<<<dim3(256, 13), 256, 0, stream>>>(Xg, Wp, biasP, Zf, Zb);
    lstm_kernel<<<128, 512, 0, stream>>>(Zf, Zb, WhhP, span_lens, feats);
    logits_kernel<<<48, 256, 0, stream>>>(feats, slot_embs, slot_mask, out);
}

// Round 3
// 641.352 us; speedup vs baseline: 1.2914x; 1.0962x over previous
//
#include <hip/hip_runtime.h>

// B=64, S=1024, D=800, MS=16, T=32, H=200, NS=12
// Nseq=1024, M=32768 (m = t*1024 + seq), gates N=1600 pad 1664, Whh K pad 224.

typedef __attribute__((ext_vector_type(4))) float f32x4;
typedef __attribute__((ext_vector_type(8))) short s16x8;

__device__ __forceinline__ unsigned short f2bf(float f) {
    union { float f; unsigned int u; } a; a.f = f;
    unsigned int u = a.u;
    u += 0x7fffu + ((u >> 16) & 1u);   // RNE
    return (unsigned short)(u >> 16);
}
__device__ __forceinline__ float bf2f(unsigned short s) {
    union { unsigned int u; float f; } a; a.u = ((unsigned int)s) << 16; return a.f;
}
__device__ __forceinline__ void async_copy16(const void* g, void* l) {
    __builtin_amdgcn_global_load_lds(
        (const __attribute__((address_space(1))) unsigned int*)g,
        (__attribute__((address_space(3))) unsigned int*)l, 16, 0, 0);
}
__device__ __forceinline__ float sigf_(float x) {
    return 1.f / (1.f + __expf(-x));
}
__device__ __forceinline__ float tanhf_(float x) {
    float ax = fabsf(x);
    float e = __expf(-2.f * ax);
    float r = (1.f - e) / (1.f + e);
    return x < 0.f ? -r : r;
}

// ---------------- kernel 1: pack weights to bf16 (padded) + bias ----------------
__global__ void pack_kernel(const float* __restrict__ Wih_f, const float* __restrict__ Wih_b,
                            const float* __restrict__ Whh_f, const float* __restrict__ Whh_b,
                            const float* __restrict__ bih_f, const float* __restrict__ bhh_f,
                            const float* __restrict__ bih_b, const float* __restrict__ bhh_b,
                            unsigned short* __restrict__ Wp, unsigned short* __restrict__ WhhP,
                            float* __restrict__ biasP)
{
    int tid = blockIdx.x * blockDim.x + threadIdx.x;
    if (tid < 1664 * 800) {
        int n = tid / 800, k = tid - n * 800;
        float v = 0.f;
        if (n < 800)       v = Wih_f[n * 800 + k];
        else if (n < 1600) v = Wih_b[(n - 800) * 800 + k];
        Wp[tid] = f2bf(v);
        return;
    }
    int t2 = tid - 1664 * 800;
    if (t2 < 1600 * 224) {
        int n = t2 / 224, k = t2 - n * 224;
        float v = 0.f;
        if (k < 200) v = (n < 800) ? Whh_f[n * 200 + k] : Whh_b[(n - 800) * 200 + k];
        WhhP[t2] = f2bf(v);
        return;
    }
    int t3 = t2 - 1600 * 224;
    if (t3 < 1664) {
        float v = 0.f;
        if (t3 < 800)       v = bih_f[t3] + bhh_f[t3];
        else if (t3 < 1600) v = bih_b[t3 - 800] + bhh_b[t3 - 800];
        biasP[t3] = v;
    }
}

// ---------------- kernel 2: gather spans + fp32->bf16 ----------------
// Xg row m = t*1024 + seq, seq = b*16 + ms
__global__ void gather_kernel(const float* __restrict__ hidden, const int* __restrict__ starts,
                              unsigned short* __restrict__ Xg)
{
    int tid = blockIdx.x * blockDim.x + threadIdx.x;   // one per 4 elements
    if (tid >= 32768 * 200) return;
    int row = tid / 200;
    int c4  = tid - row * 200;
    int t   = row >> 10, seq = row & 1023;
    int b   = seq >> 4;
    int src = starts[seq] + t;
    src = src < 1023 ? src : 1023;
    const float4 v = *(const float4*)(hidden + (size_t)(b * 1024 + src) * 800 + c4 * 4);
    ushort4 o;
    o.x = f2bf(v.x); o.y = f2bf(v.y); o.z = f2bf(v.z); o.w = f2bf(v.w);
    *(ushort4*)(Xg + (size_t)row * 800 + c4 * 4) = o;
}

// ---------------- kernel 3: GEMM Z = Xg @ Wp^T + bias ----------------
// M=32768, N=1664, K=800. Epilogue scatters to Zf/Zb[m][u] (stride 832, bf16).
__global__ __launch_bounds__(256) void gemm_kernel(const unsigned short* __restrict__ Xg,
                                                   const unsigned short* __restrict__ Wp,
                                                   const float* __restrict__ biasP,
                                                   unsigned short* __restrict__ Zf,
                                                   unsigned short* __restrict__ Zb)
{
    __shared__ __align__(16) unsigned short As[128 * 32];
    __shared__ __align__(16) unsigned short Bs[128 * 32];
    const int tid = threadIdx.x;
    const int wid = tid >> 6, lane = tid & 63;
    const int m0 = blockIdx.x * 128;
    const int n0 = blockIdx.y * 128;
    const int wm = (wid >> 1) * 64, wn = (wid & 1) * 64;
    const int l15 = lane & 15, l4 = lane >> 4;

    f32x4 acc[4][4];
#pragma unroll
    for (int i = 0; i < 4; i++)
#pragma unroll
        for (int j = 0; j < 4; j++) acc[i][j] = (f32x4){0.f, 0.f, 0.f, 0.f};

    const int r0 = tid >> 2,         kc0 = (tid & 3) * 8;
    const int r1 = (256 + tid) >> 2, kc1 = (tid & 3) * 8;
    unsigned short* AsB0 = As + (size_t)(wid * 64) * 8;
    unsigned short* AsB1 = As + (size_t)(256 + wid * 64) * 8;
    unsigned short* BsB0 = Bs + (size_t)(wid * 64) * 8;
    unsigned short* BsB1 = Bs + (size_t)(256 + wid * 64) * 8;

    for (int kb = 0; kb < 25; ++kb) {
        const int kk = kb * 32;
        async_copy16(Xg + (size_t)(m0 + r0) * 800 + kk + kc0, AsB0);
        async_copy16(Xg + (size_t)(m0 + r1) * 800 + kk + kc1, AsB1);
        async_copy16(Wp + (size_t)(n0 + r0) * 800 + kk + kc0, BsB0);
        async_copy16(Wp + (size_t)(n0 + r1) * 800 + kk + kc1, BsB1);
        __syncthreads();

        s16x8 a[4], b[4];
#pragma unroll
        for (int i = 0; i < 4; i++)
            a[i] = *(const s16x8*)(As + (wm + i * 16 + l15) * 32 + l4 * 8);
#pragma unroll
        for (int i = 0; i < 4; i++)
            b[i] = *(const s16x8*)(Bs + (wn + i * 16 + l15) * 32 + l4 * 8);
#pragma unroll
        for (int im = 0; im < 4; im++)
#pragma unroll
            for (int in = 0; in < 4; in++)
                acc[im][in] = __builtin_amdgcn_mfma_f32_16x16x32_bf16(a[im], b[in], acc[im][in], 0, 0, 0);
        __syncthreads();
    }

    float bias_v[4];
#pragma unroll
    for (int in = 0; in < 4; in++) bias_v[in] = biasP[n0 + wn + in * 16 + l15];

#pragma unroll
    for (int im = 0; im < 4; im++) {
        int mbase = m0 + wm + im * 16 + l4 * 4;
#pragma unroll
        for (int in = 0; in < 4; in++) {
            int col = n0 + wn + in * 16 + l15;
            if (col < 1600) {
                int d = col >= 800;
                int u = col - d * 800;
                unsigned short* Zd = d ? Zb : Zf;
#pragma unroll
                for (int r = 0; r < 4; r++)
                    Zd[(size_t)(mbase + r) * 832 + u] = f2bf(acc[im][in][r] + bias_v[in]);
            }
        }
    }
}

// ---------------- kernel 4: masked bidirectional LSTM + pooled feats ----------------
// 128 blocks x 512 threads: dir = bx>>6, g = bx&63 (16 sequences, m=16 MFMA rows).
// Whh tiles 0..23 register-resident across all 32 steps (3 tiles/wave x 28 VGPR);
// tiles 24..49 streamed from L2 each step. A-fragments (h) loaded once per step.
// Phase 2 vectorized over 4-unit groups: f32x4 zm reads, ushort4 zbuf reads,
// register c/feat state, ushort4 h writes.
__global__ __launch_bounds__(512, 2) void lstm_kernel(const unsigned short* __restrict__ Zf,
                                                      const unsigned short* __restrict__ Zb,
                                                      const unsigned short* __restrict__ WhhP,
                                                      const int* __restrict__ span_lens,
                                                      float* __restrict__ feats)
{
    __shared__ __align__(16) unsigned short h_lds[16 * 232];     // A operand [s][k pad 224], stride 232
    __shared__ __align__(16) unsigned short zbuf[2][16 * 832];   // staged input-z tiles (bf16)
    __shared__ __align__(16) float zm[16 * 816];                 // recurrent z [s][col], stride 816

    const int bx = blockIdx.x;
    const int dir = bx >> 6;
    const int g = bx & 63;
    const int tid = threadIdx.x;
    const int w = tid >> 6, lane = tid & 63;
    const int l15 = lane & 15, l4 = lane >> 4;
    const unsigned short* __restrict__ Zd = dir ? Zb : Zf;

    // ---- preload register-resident Whh tiles (j = w*3 + rt, rt<3 -> tiles 0..23)
    s16x8 breg[3][7];
#pragma unroll
    for (int rt = 0; rt < 3; ++rt) {
        const int colg = dir * 800 + (w * 3 + rt) * 16 + l15;
        const unsigned short* wrow = WhhP + (size_t)colg * 224 + l4 * 8;
#pragma unroll
        for (int kk = 0; kk < 7; ++kk)
            breg[rt][kk] = *(const s16x8*)(wrow + kk * 32);
    }

    for (int i = tid; i < 16 * 232; i += 512) h_lds[i] = 0;

    // ---- phase-2 state: up to 2 groups of (sample s, 4 units u4*4..u4*4+3)
    f32x4 c_st[2], f_st[2];
    int s_g[2], u4_g[2], len_g[2], valid[2];
#pragma unroll
    for (int q = 0; q < 2; ++q) {
        c_st[q] = (f32x4){0.f, 0.f, 0.f, 0.f};
        f_st[q] = (f32x4){0.f, 0.f, 0.f, 0.f};
        int grp = tid + q * 512;
        valid[q] = (grp < 800);
        int s = valid[q] ? (grp / 50) : 0;
        int u4 = valid[q] ? (grp - s * 50) : 0;
        s_g[q] = s; u4_g[q] = u4;
        len_g[q] = valid[q] ? span_lens[g * 16 + s] : -1;
    }

    // ---- prefetch step-0 tile into zbuf[0]
    {
        const int t0 = dir ? 31 : 0;
        const unsigned short* gb = Zd + (size_t)(t0 * 1024 + g * 16) * 832;
        for (int c = w; c < 26; c += 8)
            async_copy16(gb + c * 512 + lane * 8, (unsigned short*)zbuf[0] + c * 512);
    }
    __syncthreads();

    for (int step = 0; step < 32; ++step) {
        const int t = dir ? (31 - step) : step;
        const int cur = step & 1, nxt = cur ^ 1;
        if (step < 31) {
            const int tn = dir ? (t - 1) : (t + 1);
            const unsigned short* gb = Zd + (size_t)(tn * 1024 + g * 16) * 832;
            for (int c = w; c < 26; c += 8)
                async_copy16(gb + c * 512 + lane * 8, (unsigned short*)zbuf[nxt] + c * 512);
        }

        // ---- phase 1: zm = h @ Whh^T
        // A-fragments once per step
        s16x8 afr[7];
        {
            const unsigned short* hrow = h_lds + l15 * 232 + l4 * 8;
#pragma unroll
            for (int kk = 0; kk < 7; ++kk)
                afr[kk] = *(const s16x8*)(hrow + kk * 32);
        }
        // register-resident tiles
#pragma unroll
        for (int rt = 0; rt < 3; ++rt) {
            f32x4 acc = (f32x4){0.f, 0.f, 0.f, 0.f};
#pragma unroll
            for (int kk = 0; kk < 7; ++kk)
                acc = __builtin_amdgcn_mfma_f32_16x16x32_bf16(afr[kk], breg[rt][kk], acc, 0, 0, 0);
            const int col = (w * 3 + rt) * 16 + l15;
#pragma unroll
            for (int r = 0; r < 4; ++r)
                zm[(l4 * 4 + r) * 816 + col] = acc[r];
        }
        // streamed tiles (L2)
        for (int j = 24 + w; j < 50; j += 8) {
            const int colg = dir * 800 + j * 16 + l15;
            const unsigned short* wrow = WhhP + (size_t)colg * 224 + l4 * 8;
            s16x8 bs[7];
#pragma unroll
            for (int kk = 0; kk < 7; ++kk)
                bs[kk] = *(const s16x8*)(wrow + kk * 32);
            f32x4 acc = (f32x4){0.f, 0.f, 0.f, 0.f};
#pragma unroll
            for (int kk = 0; kk < 7; ++kk)
                acc = __builtin_amdgcn_mfma_f32_16x16x32_bf16(afr[kk], bs[kk], acc, 0, 0, 0);
#pragma unroll
            for (int r = 0; r < 4; ++r)
                zm[(l4 * 4 + r) * 816 + j * 16 + l15] = acc[r];
        }
        __syncthreads();   // zm visible; zbuf[nxt] DMA drained; zbuf[cur] ready

        // ---- phase 2: gates + state update (masked), 4 units per group
#pragma unroll
        for (int q = 0; q < 2; ++q) {
            if (valid[q] && t < len_g[q]) {
                const int s = s_g[q], u4 = u4_g[q];
                const float* zr = zm + s * 816 + u4 * 4;
                f32x4 zi = *(const f32x4*)(zr);
                f32x4 zf = *(const f32x4*)(zr + 200);
                f32x4 zg = *(const f32x4*)(zr + 400);
                f32x4 zo = *(const f32x4*)(zr + 600);
                const unsigned short* zb = zbuf[cur] + s * 832 + u4 * 4;
                ushort4 bi = *(const ushort4*)(zb);
                ushort4 bf = *(const ushort4*)(zb + 200);
                ushort4 bg = *(const ushort4*)(zb + 400);
                ushort4 bo = *(const ushort4*)(zb + 600);
                zi[0] += bf2f(bi.x); zi[1] += bf2f(bi.y); zi[2] += bf2f(bi.z); zi[3] += bf2f(bi.w);
                zf[0] += bf2f(bf.x); zf[1] += bf2f(bf.y); zf[2] += bf2f(bf.z); zf[3] += bf2f(bf.w);
                zg[0] += bf2f(bg.x); zg[1] += bf2f(bg.y); zg[2] += bf2f(bg.z); zg[3] += bf2f(bg.w);
                zo[0] += bf2f(bo.x); zo[1] += bf2f(bo.y); zo[2] += bf2f(bo.z); zo[3] += bf2f(bo.w);
                f32x4 cn, hn;
#pragma unroll
                for (int r = 0; r < 4; ++r) {
                    cn[r] = sigf_(zf[r]) * c_st[q][r] + sigf_(zi[r]) * tanhf_(zg[r]);
                    hn[r] = sigf_(zo[r]) * tanhf_(cn[r]);
                }
                c_st[q] = cn;
                f_st[q] += hn;
                ushort4 hp;
                hp.x = f2bf(hn[0]); hp.y = f2bf(hn[1]); hp.z = f2bf(hn[2]); hp.w = f2bf(hn[3]);
                *(ushort4*)(h_lds + s * 232 + u4 * 4) = hp;
            }
        }
        __syncthreads();   // h stable for next phase 1; zbuf[cur] free
    }

#pragma unroll
    for (int q = 0; q < 2; ++q) {
        if (valid[q]) {
            float* fp = feats + (size_t)(g * 16 + s_g[q]) * 400 + dir * 200 + u4_g[q] * 4;
            *(f32x4*)fp = f_st[q];
        }
    }
}

// ---------------- kernel 5: logits = feats @ slot_embs * slot_mask ----------------
__global__ void logits_kernel(const float* __restrict__ feats, const float* __restrict__ se,
                              const float* __restrict__ slot_mask, float* __restrict__ out)
{
    int tid = blockIdx.x * blockDim.x + threadIdx.x;
    if (tid >= 1024 * 12) return;
    int n = tid / 12, ns = tid - n * 12;
    const float* f = feats + (size_t)n * 400;
    float acc = 0.f;
    for (int u = 0; u < 400; ++u) acc += f[u] * se[u * 12 + ns];
    out[tid] = acc * slot_mask[n];
}

extern "C" void kernel_launch(void* const* d_in, const int* in_sizes, int n_in,
                              void* d_out, int out_size, void* d_ws, size_t ws_size,
                              hipStream_t stream)
{
    const float* hidden      = (const float*)d_in[0];
    const float* Wih_f       = (const float*)d_in[1];
    const float* Whh_f       = (const float*)d_in[2];
    const float* bih_f       = (const float*)d_in[3];
    const float* bhh_f       = (const float*)d_in[4];
    const float* Wih_b       = (const float*)d_in[5];
    const float* Whh_b       = (const float*)d_in[6];
    const float* bih_b       = (const float*)d_in[7];
    const float* bhh_b       = (const float*)d_in[8];
    const float* slot_embs   = (const float*)d_in[9];
    const int*   span_starts = (const int*)d_in[10];
    const int*   span_lens   = (const int*)d_in[11];
    const float* slot_mask   = (const float*)d_in[12];
    float* out = (float*)d_out;

    char* ws = (char*)d_ws;
    unsigned short* Xg    = (unsigned short*)(ws + 0);           //  52,428,800
    unsigned short* Wp    = (unsigned short*)(ws + 52428800);    //   2,662,400
    unsigned short* WhhP  = (unsigned short*)(ws + 55091200);    //     716,800
    float*          biasP = (float*)         (ws + 55808000);    //       6,656
    unsigned short* Zf    = (unsigned short*)(ws + 55814656);    //  54,525,952 (32768 x 832 bf16)
    unsigned short* Zb    = (unsigned short*)(ws + 110340608);   //  54,525,952
    float*          feats = (float*)         (ws + 164866560);   //   1,638,400
    // total: 166,504,960 B

    {
        int total = 1664 * 800 + 1600 * 224 + 1664;
        int blocks = (total + 255) / 256;
        pack_kernel<<<blocks, 256, 0, stream>>>(Wih_f, Wih_b, Whh_f, Whh_b,
                                                bih_f, bhh_f, bih_b, bhh_b,
                                                Wp, WhhP, biasP);
    }
    gather_kernel<<<25600, 256, 0, stream>>>(hidden, span_starts, Xg);
    gemm_kernel<<<dim3(256, 13), 256, 0, stream>>>(Xg, Wp, biasP, Zf, Zb);
    lstm_kernel<<<128, 512, 0, stream>>>(Zf, Zb, WhhP, span_lens, feats);
    logits_kernel<<<48, 256, 0, stream>>>(feats, slot_embs, slot_mask, out);
}